// Round 16
// baseline (127.570 us; speedup 1.0000x reference)
//
#include <hip/hip_runtime.h>

// Linear attention (B=8, T=2048, D=512), chunked, bf16 MFMA, fp32 acc.
// R16: R15 + G-dedup: G=tril(QK^T)+den moved from k8_y (computed 2x, per ch)
// into k8_mg (computed once, alongside mtst). y = 2 pure GEMMs + divide.
//   k_pre   : bf16(x) + W^T transposes                          (4352 blocks)
//   k8_qkvt : q | kk+Kt^T+zsum | Vt^T fused per block           (512 blocks, 128KB LDS)
//   k8_mg   : St-prefix GEMM (256 blk) + G+den (128 blk)        (384 blocks, 96KB LDS)
//   k8_y    : y = (Q St^T + G Vt^T)/den                         (256 blocks, 96KB LDS)
//   k8_out  : out = y Wp^T (fp32)                               (256 blocks)
// All GEMMs are C = A * B^T with A:[M][K], B:[N][K] row-major bf16.

typedef __attribute__((ext_vector_type(4))) float f32x4;
typedef __attribute__((ext_vector_type(8))) __bf16 bf16x8;
typedef __attribute__((ext_vector_type(8))) unsigned short ushort8;

// ---- ws layout (byte offsets) ----
constexpr size_t OFF_XB  = 0;                  // bf16 [16384][512]
constexpr size_t OFF_WT  = OFF_XB + 16777216;  // bf16 4x [512][512]
constexpr size_t OFF_Q   = OFF_WT + 2097152;   // bf16 [16384][512]
constexpr size_t OFF_KK  = OFF_Q  + 16777216;  // bf16 [16384][512]
constexpr size_t OFF_KT  = OFF_KK + 16777216;  // bf16 [512][16384]
constexpr size_t OFF_VT  = OFF_KT + 16777216;  // bf16 [512][16384]
constexpr size_t OFF_G   = OFF_VT + 16777216;  // bf16 [64][256][256]
constexpr size_t OFF_MT  = OFF_G  + 8388608;   // bf16 [64][512][512] St (prefixed)
constexpr size_t OFF_Y   = OFF_MT + 33554432;  // bf16 [16384][512]
constexpr size_t OFF_ZP  = OFF_Y  + 16777216;  // f32  [128][512] col sums of kk
constexpr size_t OFF_DEN = OFF_ZP + 262144;    // f32  [16384]
constexpr size_t WS_NEED = OFF_DEN + 65536;

__device__ __forceinline__ unsigned short bfbits(float f) {
  __bf16 h = (__bf16)f;
  return __builtin_bit_cast(unsigned short, h);
}
__device__ __forceinline__ float bff(unsigned short u) {
  return (float)__builtin_bit_cast(__bf16, u);
}

__device__ __forceinline__ void gload16(const void* g, void* l) {
  __builtin_amdgcn_global_load_lds((const __attribute__((address_space(1))) void*)g,
                                   (__attribute__((address_space(3))) void*)l, 16, 0, 0);
}

// ============ 128B-row stage/frag pair — proven 0-conflict ============
__device__ __forceinline__ void stage_half(const char* gRow0, size_t ld2, int k0b,
                                           char* ldsHalf, int w, int lane) {
#pragma unroll
  for (int i = 0; i < 2; ++i) {
    int L = (w << 10) + (lane << 4) + (i << 13);
    int r = L >> 7;
    int cb = (L & 127) ^ ((r & 7) << 4);
    gload16(gRow0 + (size_t)r * ld2 + k0b + cb, ldsHalf + (w << 10) + (i << 13));
  }
}

__device__ __forceinline__ void stage_q64(const char* gRow0, size_t ld2, int k0b,
                                          char* lds, int tid) {
  int L = tid << 4;
  int r = L >> 7;
  int cb = (L & 127) ^ ((r & 7) << 4);
  gload16(gRow0 + (size_t)r * ld2 + k0b + cb, lds + L);
}

__device__ __forceinline__ const bf16x8* frag_at(const char* halfBase, int rowInHalf,
                                                 int colByte) {
  int lin = (rowInHalf << 7) + colByte;
  lin ^= (rowInHalf & 7) << 4;
  return (const bf16x8*)(halfBase + lin);
}

// ======================= 128x256 8-wave 4-phase core =======================
#define QUADH(mh, nh)                                                                  \
  _Pragma("unroll") for (int mm = 0; mm < 2; ++mm)                                     \
  _Pragma("unroll") for (int nn = 0; nn < 2; ++nn)                                     \
  _Pragma("unroll") for (int s = 0; s < 2; ++s)                                        \
      acc[(mh)*2 + mm][(nh)*2 + nn] = __builtin_amdgcn_mfma_f32_16x16x32_bf16(         \
          af[(mh)*2 + mm][s], bg[(nh)*2 + nn][s], acc[(mh)*2 + mm][(nh)*2 + nn], 0, 0, 0);

#define PHASE_TAILH(MH, NH)                                      \
  __builtin_amdgcn_s_barrier();                                  \
  asm volatile("s_waitcnt lgkmcnt(0)" ::: "memory");             \
  __builtin_amdgcn_sched_barrier(0);                             \
  __builtin_amdgcn_s_setprio(1);                                 \
  QUADH(MH, NH);                                                 \
  __builtin_amdgcn_s_setprio(0);                                 \
  __builtin_amdgcn_s_barrier();

__device__ __forceinline__ void core8h(const char* Ab, size_t lda2, const char* Bb,
                                       size_t ldb2, int nt, char* sA, char* sB,
                                       f32x4 (&acc)[4][4], int w, int lane) {
  const int wr = w >> 2, wc = w & 3;
  const int fr = lane & 15, foB = (lane >> 4) << 4;
  const int brow = (wc & 1) << 6;
  const char* gB1 = Bb + (size_t)128 * ldb2;
  bf16x8 af[4][2], bg[4][2];

  stage_half(Ab, lda2, 0, sA + 0, w, lane);
  stage_half(Bb, ldb2, 0, sB + 0, w, lane);
  stage_half(gB1, ldb2, 0, sB + 16384, w, lane);
  if (nt > 1) {
    stage_half(Ab, lda2, 128, sA + 16384, w, lane);
    asm volatile("s_waitcnt vmcnt(2)" ::: "memory");
  } else {
    asm volatile("s_waitcnt vmcnt(0)" ::: "memory");
  }
  __builtin_amdgcn_sched_barrier(0);
  __builtin_amdgcn_s_barrier();

  for (int t = 0; t < nt; ++t) {
    const int buf = t & 1;
    const char* cA = sA + buf * 16384;
    const char* cB = sB + buf * 32768 + (wc >> 1) * 16384;
    char* nA = sA + buf * 16384;
    char* nB = sB + (buf ^ 1) * 32768;
    const int kb1 = (t + 1) << 7, kb2 = (t + 2) << 7;
    const bool stB = (t + 1 < nt), stA = (t + 2 < nt);

#pragma unroll
    for (int m = 0; m < 2; ++m)
#pragma unroll
      for (int s = 0; s < 2; ++s)
        af[m][s] = *frag_at(cA, wr * 64 + m * 16 + fr, s * 64 + foB);
#pragma unroll
    for (int n = 0; n < 2; ++n)
#pragma unroll
      for (int s = 0; s < 2; ++s)
        bg[n][s] = *frag_at(cB, brow + n * 16 + fr, s * 64 + foB);
    if (stB) stage_half(Bb, ldb2, kb1, nB + 0, w, lane);
    PHASE_TAILH(0, 0)

#pragma unroll
    for (int m = 2; m < 4; ++m)
#pragma unroll
      for (int s = 0; s < 2; ++s)
        af[m][s] = *frag_at(cA, wr * 64 + m * 16 + fr, s * 64 + foB);
    if (stB) stage_half(gB1, ldb2, kb1, nB + 16384, w, lane);
    PHASE_TAILH(1, 0)

#pragma unroll
    for (int n = 2; n < 4; ++n)
#pragma unroll
      for (int s = 0; s < 2; ++s)
        bg[n][s] = *frag_at(cB, brow + n * 16 + fr, s * 64 + foB);
    if (stA) stage_half(Ab, lda2, kb2, nA, w, lane);
    PHASE_TAILH(0, 1)

    if (t < nt - 1) {
      if (stA) {
        asm volatile("s_waitcnt vmcnt(2)" ::: "memory");
      } else {
        asm volatile("s_waitcnt vmcnt(0)" ::: "memory");
      }
      __builtin_amdgcn_sched_barrier(0);
    }
    PHASE_TAILH(1, 1)
  }
}

#define ACC4_INIT                                    \
  f32x4 acc[4][4];                                   \
  _Pragma("unroll") for (int m_ = 0; m_ < 4; ++m_)   \
  _Pragma("unroll") for (int n_ = 0; n_ < 4; ++n_)   \
      acc[m_][n_] = f32x4{0.f, 0.f, 0.f, 0.f};

#define ACC4_ZERO                                    \
  _Pragma("unroll") for (int m_ = 0; m_ < 4; ++m_)   \
  _Pragma("unroll") for (int n_ = 0; n_ < 4; ++n_)   \
      acc[m_][n_] = f32x4{0.f, 0.f, 0.f, 0.f};

// ---- z-fused qkvt (exact R9/R15) ----
__global__ __launch_bounds__(512, 2) void k8_qkvt(const ushort* __restrict__ xb,
                                                  const ushort* __restrict__ wt,
                                                  ushort* __restrict__ qb,
                                                  ushort* __restrict__ kkb,
                                                  ushort* __restrict__ Kt,
                                                  ushort* __restrict__ Vt,
                                                  float* __restrict__ zsumH) {
  extern __shared__ char smem[];
  const int o = blockIdx.x;
  const int wg = (o & 7) * 64 + (o >> 3);  // bijective: 512 % 8 == 0
  const int mt = wg >> 2, ct = wg & 3;
  const int tid = threadIdx.x, w = tid >> 6, lane = tid & 63;
  const int wr = w >> 2, wc = w & 3;
  const int fr = lane & 15, foB = (lane >> 4) << 4, q4 = (lane >> 4) << 2;
  const char* Ab = (const char*)(xb + (size_t)mt * 128 * 512);
  const char* Bz[3];
  Bz[0] = (const char*)(wt + (size_t)ct * 65536);
  Bz[1] = (const char*)(wt + 262144 + (size_t)ct * 65536);
  Bz[2] = (const char*)(wt + 524288 + (size_t)ct * 65536);
  char* sA = smem;
  char* sB0 = smem + 32768;
  char* sB1 = smem + 65536;
  char* sB2 = smem + 98304;

  f32x4 acc[3][4][2];
#pragma unroll
  for (int z = 0; z < 3; ++z)
#pragma unroll
    for (int m = 0; m < 4; ++m)
#pragma unroll
      for (int n = 0; n < 2; ++n) acc[z][m][n] = f32x4{0.f, 0.f, 0.f, 0.f};

  stage_half(Ab, 1024, 0, sA, w, lane);
  stage_half(Bz[0], 1024, 0, sB0, w, lane);
  stage_half(Bz[1], 1024, 0, sB1, w, lane);
  stage_half(Bz[2], 1024, 0, sB2, w, lane);
  asm volatile("s_waitcnt vmcnt(0)" ::: "memory");
  __builtin_amdgcn_sched_barrier(0);
  __builtin_amdgcn_s_barrier();

  for (int t = 0; t < 8; ++t) {
    const int buf = t & 1;
    const int bo = buf << 14, nbo = (buf ^ 1) << 14;
    if (t + 1 < 8) {
      const int kb = (t + 1) << 7;
      stage_half(Ab, 1024, kb, sA + nbo, w, lane);
      stage_half(Bz[0], 1024, kb, sB0 + nbo, w, lane);
      stage_half(Bz[1], 1024, kb, sB1 + nbo, w, lane);
      stage_half(Bz[2], 1024, kb, sB2 + nbo, w, lane);
    }
    bf16x8 af[4][2], bg[3][2][2];
#pragma unroll
    for (int m = 0; m < 4; ++m)
#pragma unroll
      for (int s = 0; s < 2; ++s)
        af[m][s] = *frag_at(sA + bo, wr * 64 + m * 16 + fr, s * 64 + foB);
#pragma unroll
    for (int z = 0; z < 3; ++z)
#pragma unroll
      for (int n = 0; n < 2; ++n)
#pragma unroll
        for (int s = 0; s < 2; ++s)
          bg[z][n][s] = *frag_at((z == 0 ? sB0 : z == 1 ? sB1 : sB2) + bo,
                                 wc * 32 + n * 16 + fr, s * 64 + foB);
    __builtin_amdgcn_s_setprio(1);
#pragma unroll
    for (int z = 0; z < 3; ++z)
#pragma unroll
      for (int m = 0; m < 4; ++m)
#pragma unroll
        for (int n = 0; n < 2; ++n)
#pragma unroll
          for (int s = 0; s < 2; ++s)
            acc[z][m][n] = __builtin_amdgcn_mfma_f32_16x16x32_bf16(af[m][s], bg[z][n][s],
                                                                   acc[z][m][n], 0, 0, 0);
    __builtin_amdgcn_s_setprio(0);
    if (t + 1 < 8) {
      asm volatile("s_waitcnt vmcnt(0)" ::: "memory");
    }
    __builtin_amdgcn_sched_barrier(0);
    __builtin_amdgcn_s_barrier();
  }

  const size_t row0 = (size_t)mt * 128 + wr * 64;  // t index
  const size_t col0 = (size_t)ct * 128 + wc * 32;  // d index
#pragma unroll
  for (int m = 0; m < 4; ++m)
#pragma unroll
    for (int n = 0; n < 2; ++n)
#pragma unroll
      for (int r = 0; r < 4; ++r) {
        float v = acc[0][m][n][r];
        v = v > 0.f ? v + 1.f : __expf(v);
        qb[(row0 + m * 16 + q4 + r) * 512 + col0 + n * 16 + fr] = bfbits(v);
      }
#pragma unroll
  for (int m = 0; m < 4; ++m)
#pragma unroll
    for (int n = 0; n < 2; ++n) {
      ushort4 ov;
      ov.x = bfbits(acc[2][m][n][0]);
      ov.y = bfbits(acc[2][m][n][1]);
      ov.z = bfbits(acc[2][m][n][2]);
      ov.w = bfbits(acc[2][m][n][3]);
      *(ushort4*)&Vt[(col0 + n * 16 + fr) * 16384 + row0 + m * 16 + q4] = ov;
    }
  float zs[2] = {0.f, 0.f};
#pragma unroll
  for (int m = 0; m < 4; ++m)
#pragma unroll
    for (int n = 0; n < 2; ++n) {
      float ph[4];
#pragma unroll
      for (int r = 0; r < 4; ++r) {
        float v = acc[1][m][n][r];
        ph[r] = v > 0.f ? v + 1.f : __expf(v);
        kkb[(row0 + m * 16 + q4 + r) * 512 + col0 + n * 16 + fr] = bfbits(ph[r]);
        zs[n] += ph[r];
      }
      ushort4 ov;
      ov.x = bfbits(ph[0]); ov.y = bfbits(ph[1]); ov.z = bfbits(ph[2]); ov.w = bfbits(ph[3]);
      *(ushort4*)&Kt[(col0 + n * 16 + fr) * 16384 + row0 + m * 16 + q4] = ov;
    }
#pragma unroll
  for (int n = 0; n < 2; ++n) {
    zs[n] += __shfl_xor(zs[n], 16, 64);
    zs[n] += __shfl_xor(zs[n], 32, 64);
  }
  float* zbuf = (float*)smem;
  if (lane < 16) {
#pragma unroll
    for (int n = 0; n < 2; ++n) zbuf[wr * 128 + wc * 32 + n * 16 + fr] = zs[n];
  }
  __syncthreads();
  if (tid < 128)
    zsumH[(size_t)mt * 512 + ct * 128 + tid] = zbuf[tid] + zbuf[128 + tid];
}

// ---- k8_mg: bx<256 = St-prefix GEMM (XCD-pinned); bx>=256 = G + den ----
__global__ __launch_bounds__(512, 2) void k8_mg(const ushort* __restrict__ Kt,
                                                const ushort* __restrict__ Vt,
                                                const ushort* __restrict__ qb,
                                                const ushort* __restrict__ kkb,
                                                const float* __restrict__ zsumH,
                                                ushort* __restrict__ Mt,
                                                ushort* __restrict__ Gg,
                                                float* __restrict__ den) {
  extern __shared__ char smem[];
  const int bx = blockIdx.x;
  const int tid = threadIdx.x, w = tid >> 6, lane = tid & 63;
  const int wr = w >> 2, wc = w & 3, fr = lane & 15;
  const int foB = (lane >> 4) << 4, q4 = (lane >> 4) << 2;
  if (bx < 256) {  // ---- mtst: chunk b pinned to XCD b ----
    const int b = bx & 7, r8 = bx >> 3;
    const int et = r8 >> 3, dt = r8 & 7;
    const char* Ab = (const char*)(Vt + (size_t)et * 128 * 16384 + b * 2048);
    const char* Bb = (const char*)(Kt + (size_t)dt * 64 * 16384 + b * 2048);
    f32x4 acc[4];
#pragma unroll
    for (int m = 0; m < 4; ++m) acc[m] = f32x4{0.f, 0.f, 0.f, 0.f};

    stage_half(Ab, 32768, 0, smem, w, lane);
    stage_q64(Bb, 32768, 0, smem + 32768, tid);
    asm volatile("s_waitcnt vmcnt(0)" ::: "memory");
    __builtin_amdgcn_sched_barrier(0);
    __builtin_amdgcn_s_barrier();

    const int colg = dt * 64 + wc * 16 + fr;
    for (int kk = 0; kk < 32; ++kk) {
      const int c = kk >> 2, buf = kk & 1;
      if ((kk & 3) == 0) {
        ushort* Sc = Mt + (size_t)(b * 8 + c) * 262144 + colg;
#pragma unroll
        for (int m = 0; m < 4; ++m)
#pragma unroll
          for (int r = 0; r < 4; ++r)
            Sc[(size_t)(et * 128 + wr * 64 + m * 16 + q4 + r) * 512] = bfbits(acc[m][r]);
      }
      if (kk + 1 < 32) {
        const int k0b = ((kk + 1) >> 2) * 512 + ((kk + 1) & 3) * 128;
        stage_half(Ab, 32768, k0b, smem + ((buf ^ 1) << 14), w, lane);
        stage_q64(Bb, 32768, k0b, smem + 32768 + ((buf ^ 1) << 13), tid);
      }
      const char* cA = smem + (buf << 14);
      const char* cB = smem + 32768 + (buf << 13);
      bf16x8 af[4][2], bg[2];
#pragma unroll
      for (int s = 0; s < 2; ++s) bg[s] = *frag_at(cB, wc * 16 + fr, s * 64 + foB);
#pragma unroll
      for (int m = 0; m < 4; ++m)
#pragma unroll
        for (int s = 0; s < 2; ++s)
          af[m][s] = *frag_at(cA, wr * 64 + m * 16 + fr, s * 64 + foB);
      __builtin_amdgcn_s_setprio(1);
#pragma unroll
      for (int m = 0; m < 4; ++m)
#pragma unroll
        for (int s = 0; s < 2; ++s)
          acc[m] = __builtin_amdgcn_mfma_f32_16x16x32_bf16(af[m][s], bg[s], acc[m], 0, 0, 0);
      __builtin_amdgcn_s_setprio(0);
      asm volatile("s_waitcnt vmcnt(0)" ::: "memory");
      __builtin_amdgcn_sched_barrier(0);
      __builtin_amdgcn_s_barrier();
    }
  } else {  // ---- G = tril(Q_c K_c^T) + den ----
    const int g = bx - 256;
    const int bc = g >> 1, rh = g & 1;
    const int b = bc >> 3, c = bc & 7;
    char* sA = smem;
    char* sB = smem + 32768;
    ACC4_INIT
    core8h((const char*)(qb + (size_t)bc * 131072 + (size_t)rh * 65536), 1024,
           (const char*)(kkb + (size_t)bc * 131072), 1024, 8, sA, sB, acc, w, lane);

    float rs[4][4];
#pragma unroll
    for (int m = 0; m < 4; ++m)
#pragma unroll
      for (int r = 0; r < 4; ++r) rs[m][r] = 0.f;
#pragma unroll
    for (int m = 0; m < 4; ++m)
#pragma unroll
      for (int n = 0; n < 4; ++n)
#pragma unroll
        for (int r = 0; r < 4; ++r) {
          int rowL = wr * 64 + m * 16 + q4 + r;
          int col = wc * 64 + n * 16 + fr;
          float v = (col <= rh * 128 + rowL) ? acc[m][n][r] : 0.f;
          rs[m][r] += v;
          Gg[(size_t)bc * 65536 + (size_t)(rh * 128 + rowL) * 256 + col] = bfbits(v);
        }
#pragma unroll
    for (int m = 0; m < 4; ++m)
#pragma unroll
      for (int r = 0; r < 4; ++r) {
        rs[m][r] += __shfl_xor(rs[m][r], 1, 64);
        rs[m][r] += __shfl_xor(rs[m][r], 2, 64);
        rs[m][r] += __shfl_xor(rs[m][r], 4, 64);
        rs[m][r] += __shfl_xor(rs[m][r], 8, 64);
      }
    float* red = (float*)sA;   // core8h ended with barrier; LDS reusable
    float* zpl = red + 512;
    if (fr == 0) {
#pragma unroll
      for (int m = 0; m < 4; ++m)
#pragma unroll
        for (int r = 0; r < 4; ++r) red[wc * 128 + wr * 64 + m * 16 + q4 + r] = rs[m][r];
    }
    {
      float a = 0.f;
      for (int cp = 0; cp < c; ++cp)
        a += zsumH[(size_t)((b * 8 + cp) * 2) * 512 + tid] +
             zsumH[(size_t)((b * 8 + cp) * 2 + 1) * 512 + tid];
      zpl[tid] = a;
    }
    __syncthreads();
    {
      int rl = tid >> 2, quarter = tid & 3;
      int trow = bc * 256 + rh * 128 + rl;
      const ushort* qrow = qb + (size_t)trow * 512 + quarter * 128;
      const float* zq = zpl + quarter * 128;
      float s = 0.f;
      for (int j = 0; j < 128; j += 8) {
        ushort8 qv = *(const ushort8*)&qrow[j];
#pragma unroll
        for (int u = 0; u < 8; ++u) s = fmaf(bff(qv[u]), zq[j + u], s);
      }
      s += __shfl_xor(s, 1, 64);
      s += __shfl_xor(s, 2, 64);
      if (quarter == 0)
        den[trow] = s + red[rl] + red[128 + rl] + red[256 + rl] + red[384 + rl] + 1e-6f;
    }
  }
}

// ---- y = (Q St^T + G Vt^T)/den : 256 blocks, two core8h calls ----
__global__ __launch_bounds__(512, 2) void k8_y(const ushort* __restrict__ qb,
                                               const ushort* __restrict__ Gg,
                                               const ushort* __restrict__ St,
                                               const ushort* __restrict__ Vt,
                                               const float* __restrict__ den,
                                               ushort* __restrict__ Y) {
  extern __shared__ char smem[];
  const int o = blockIdx.x;
  const int wg = (o & 7) * 32 + (o >> 3);
  const int bc = wg >> 2, rh = (wg >> 1) & 1, ch = wg & 1;
  const int tid = threadIdx.x, w = tid >> 6, lane = tid & 63;
  const int wr = w >> 2, wc = w & 3, fr = lane & 15, q4 = (lane >> 4) << 2;
  char* sA = smem;
  char* sB = smem + 32768;

  ACC4_INIT
  core8h((const char*)(qb + (size_t)bc * 131072 + (size_t)rh * 65536), 1024,
         (const char*)(St + (size_t)bc * 262144 + (size_t)ch * 131072), 1024, 8,
         sA, sB, acc, w, lane);
  core8h((const char*)(Gg + (size_t)bc * 65536 + (size_t)rh * 32768), 512,
         (const char*)(Vt + (size_t)ch * 256 * 16384 + (size_t)bc * 256), 32768,
         rh ? 4 : 2, sA, sB, acc, w, lane);

  float dinv[4][4];
#pragma unroll
  for (int m = 0; m < 4; ++m)
#pragma unroll
    for (int r = 0; r < 4; ++r)
      dinv[m][r] = 1.f / den[bc * 256 + rh * 128 + wr * 64 + m * 16 + q4 + r];
#pragma unroll
  for (int m = 0; m < 4; ++m)
#pragma unroll
    for (int n = 0; n < 4; ++n)
#pragma unroll
      for (int r = 0; r < 4; ++r) {
        size_t row = (size_t)bc * 256 + rh * 128 + wr * 64 + m * 16 + q4 + r;
        size_t col = (size_t)ch * 256 + wc * 64 + n * 16 + fr;
        Y[row * 512 + col] = bfbits(acc[m][n][r] * dinv[m][r]);
      }
}

// ---- out = Y WpT^T (fp32) : 256 blocks ----
__global__ __launch_bounds__(512, 2) void k8_out(const ushort* __restrict__ Y,
                                                 const ushort* __restrict__ wt,
                                                 float* __restrict__ out) {
  extern __shared__ char smem[];
  const int o = blockIdx.x;
  const int wg = (o & 7) * 32 + (o >> 3);
  const int mt = wg >> 1, ct = wg & 1;
  const int tid = threadIdx.x, w = tid >> 6, lane = tid & 63;
  ACC4_INIT
  core8h((const char*)(Y + (size_t)mt * 65536), 1024,
         (const char*)(wt + 786432 + (size_t)ct * 131072), 1024, 8,
         smem, smem + 32768, acc, w, lane);
  const int wr = w >> 2, wc = w & 3, fr = lane & 15, q4 = (lane >> 4) << 2;
  const size_t row0 = (size_t)mt * 128 + wr * 64;
  const size_t col0 = (size_t)ct * 256 + wc * 64;
#pragma unroll
  for (int m = 0; m < 4; ++m)
#pragma unroll
    for (int n = 0; n < 4; ++n)
#pragma unroll
      for (int r = 0; r < 4; ++r)
        out[(row0 + m * 16 + q4 + r) * 512 + col0 + n * 16 + fr] = acc[m][n][r];
}

// ---- x -> bf16 (4096 blocks) + W -> W^T bf16 (256 blocks) ----
__global__ __launch_bounds__(256) void k_pre(const float* __restrict__ x,
                                             const float* __restrict__ Wq,
                                             const float* __restrict__ Wk,
                                             const float* __restrict__ Wv,
                                             const float* __restrict__ Wp,
                                             ushort* __restrict__ xb,
                                             ushort* __restrict__ wt) {
  __shared__ float tile[64][65];
  if (blockIdx.x < 4096) {
    size_t i = ((size_t)blockIdx.x * 256 + threadIdx.x) * 8;
    float4 f0 = *(const float4*)&x[i], f1 = *(const float4*)&x[i + 4];
    ushort8 ov;
    ov[0] = bfbits(f0.x); ov[1] = bfbits(f0.y); ov[2] = bfbits(f0.z); ov[3] = bfbits(f0.w);
    ov[4] = bfbits(f1.x); ov[5] = bfbits(f1.y); ov[6] = bfbits(f1.z); ov[7] = bfbits(f1.w);
    *(ushort8*)&xb[i] = ov;
  } else {
    const int g = blockIdx.x - 4096;
    const int bz = g >> 6, rem = g & 63, bxw = rem >> 3, byw = rem & 7;
    const float* src = bz == 0 ? Wq : bz == 1 ? Wk : bz == 2 ? Wv : Wp;
    ushort* dst = wt + (size_t)bz * 262144;
    const int d0 = bxw * 64, n0 = byw * 64;
    const int tr = threadIdx.x >> 4, tc = (threadIdx.x & 15) << 2;
#pragma unroll
    for (int it = 0; it < 4; ++it) {
      float4 f = *(const float4*)&src[(size_t)(d0 + it * 16 + tr) * 512 + n0 + tc];
      tile[it * 16 + tr][tc + 0] = f.x;
      tile[it * 16 + tr][tc + 1] = f.y;
      tile[it * 16 + tr][tc + 2] = f.z;
      tile[it * 16 + tr][tc + 3] = f.w;
    }
    __syncthreads();
#pragma unroll
    for (int it = 0; it < 4; ++it) {
      int n = it * 16 + tr;
      ushort4 ov;
      ov.x = bfbits(tile[tc + 0][n]);
      ov.y = bfbits(tile[tc + 1][n]);
      ov.z = bfbits(tile[tc + 2][n]);
      ov.w = bfbits(tile[tc + 3][n]);
      *(ushort4*)&dst[(size_t)(n0 + n) * 512 + d0 + tc] = ov;
    }
  }
}

extern "C" void kernel_launch(void* const* d_in, const int* in_sizes, int n_in,
                              void* d_out, int out_size, void* d_ws, size_t ws_size,
                              hipStream_t stream) {
  const float* x  = (const float*)d_in[0];
  const float* Wq = (const float*)d_in[1];
  const float* Wk = (const float*)d_in[2];
  const float* Wv = (const float*)d_in[3];
  const float* Wp = (const float*)d_in[4];
  float* out = (float*)d_out;
  char* ws8 = (char*)d_ws;
  if (ws_size < WS_NEED) return;

  ushort* xb  = (ushort*)(ws8 + OFF_XB);
  ushort* wt  = (ushort*)(ws8 + OFF_WT);
  ushort* qb  = (ushort*)(ws8 + OFF_Q);
  ushort* kkb = (ushort*)(ws8 + OFF_KK);
  ushort* Kt  = (ushort*)(ws8 + OFF_KT);
  ushort* Vt  = (ushort*)(ws8 + OFF_VT);
  ushort* Gg  = (ushort*)(ws8 + OFF_G);
  ushort* Mt  = (ushort*)(ws8 + OFF_MT);
  ushort* Y   = (ushort*)(ws8 + OFF_Y);
  float*  zpH = (float*)(ws8 + OFF_ZP);
  float*  den = (float*)(ws8 + OFF_DEN);

  constexpr int SMEM_QKVT = 131072, SMEM_H = 98304;
  hipFuncSetAttribute((const void*)k8_qkvt, hipFuncAttributeMaxDynamicSharedMemorySize, SMEM_QKVT);
  hipFuncSetAttribute((const void*)k8_mg,   hipFuncAttributeMaxDynamicSharedMemorySize, SMEM_H);
  hipFuncSetAttribute((const void*)k8_y,    hipFuncAttributeMaxDynamicSharedMemorySize, SMEM_H);
  hipFuncSetAttribute((const void*)k8_out,  hipFuncAttributeMaxDynamicSharedMemorySize, SMEM_H);

  k_pre<<<4352, 256, 0, stream>>>(x, Wq, Wk, Wv, Wp, xb, wt);
  k8_qkvt<<<512, 512, SMEM_QKVT, stream>>>(xb, wt, qb, kkb, Kt, Vt, zpH);
  k8_mg<<<384, 512, SMEM_H, stream>>>(Kt, Vt, qb, kkb, zpH, Mt, Gg, den);
  k8_y<<<256, 512, SMEM_H, stream>>>(qb, Gg, Mt, Vt, den, Y);
  k8_out<<<256, 512, SMEM_H, stream>>>(Y, wt, out);
}

// Round 17
// 127.119 us; speedup vs baseline: 1.0035x; 1.0035x over previous
//
#include <hip/hip_runtime.h>

// Linear attention (B=8, T=2048, D=512), chunked, bf16 MFMA, fp32 acc.
// R17 = R15 (session best, 127.2us): R9 pipeline + mtst XCD-pinning.
//   k_pre   : bf16(x) + W^T transposes                          (4352 blocks)
//   k8_qkvt : q | kk+Kt^T+zsum | Vt^T fused per block           (512 blocks, 128KB LDS)
//   k8_mtst : St = exclusive-chunk-prefix(Vt_c Kt_c^T) fused    (256 blocks, XCD-pinned)
//   k8_y    : G=tril(QK^T)->LDS, den in-block, y=(QSt^T+GVt^T)/den (256 blocks, 160KB LDS)
//   k8_out  : out = y Wp^T (fp32)                               (256 blocks)
// All GEMMs are C = A * B^T with A:[M][K], B:[N][K] row-major bf16.

typedef __attribute__((ext_vector_type(4))) float f32x4;
typedef __attribute__((ext_vector_type(8))) __bf16 bf16x8;
typedef __attribute__((ext_vector_type(8))) unsigned short ushort8;

// ---- ws layout (byte offsets) ----
constexpr size_t OFF_XB  = 0;                  // bf16 [16384][512]
constexpr size_t OFF_WT  = OFF_XB + 16777216;  // bf16 4x [512][512] (WqT,WkT,WvT,WpT)
constexpr size_t OFF_Q   = OFF_WT + 2097152;   // bf16 [16384][512]
constexpr size_t OFF_KK  = OFF_Q  + 16777216;  // bf16 [16384][512]
constexpr size_t OFF_KT  = OFF_KK + 16777216;  // bf16 [512][16384]
constexpr size_t OFF_VT  = OFF_KT + 16777216;  // bf16 [512][16384]
constexpr size_t OFF_MT  = OFF_VT + 16777216;  // bf16 [64][512][512] St (prefixed)
constexpr size_t OFF_Y   = OFF_MT + 33554432;  // bf16 [16384][512]
constexpr size_t OFF_ZP  = OFF_Y  + 16777216;  // f32  [128][512] col sums of kk
constexpr size_t WS_NEED = OFF_ZP + 262144;

__device__ __forceinline__ unsigned short bfbits(float f) {
  __bf16 h = (__bf16)f;
  return __builtin_bit_cast(unsigned short, h);
}
__device__ __forceinline__ float bff(unsigned short u) {
  return (float)__builtin_bit_cast(__bf16, u);
}

__device__ __forceinline__ void gload16(const void* g, void* l) {
  __builtin_amdgcn_global_load_lds((const __attribute__((address_space(1))) void*)g,
                                   (__attribute__((address_space(3))) void*)l, 16, 0, 0);
}

// ============ 128B-row stage/frag pair — proven 0-conflict ============
__device__ __forceinline__ void stage_half(const char* gRow0, size_t ld2, int k0b,
                                           char* ldsHalf, int w, int lane) {
#pragma unroll
  for (int i = 0; i < 2; ++i) {
    int L = (w << 10) + (lane << 4) + (i << 13);
    int r = L >> 7;
    int cb = (L & 127) ^ ((r & 7) << 4);
    gload16(gRow0 + (size_t)r * ld2 + k0b + cb, ldsHalf + (w << 10) + (i << 13));
  }
}

__device__ __forceinline__ void stage_q64(const char* gRow0, size_t ld2, int k0b,
                                          char* lds, int tid) {
  int L = tid << 4;
  int r = L >> 7;
  int cb = (L & 127) ^ ((r & 7) << 4);
  gload16(gRow0 + (size_t)r * ld2 + k0b + cb, lds + L);
}

__device__ __forceinline__ const bf16x8* frag_at(const char* halfBase, int rowInHalf,
                                                 int colByte) {
  int lin = (rowInHalf << 7) + colByte;
  lin ^= (rowInHalf & 7) << 4;
  return (const bf16x8*)(halfBase + lin);
}

// ======================= 128x256 8-wave 4-phase core (y, out) =======================
#define QUADH(mh, nh)                                                                  \
  _Pragma("unroll") for (int mm = 0; mm < 2; ++mm)                                     \
  _Pragma("unroll") for (int nn = 0; nn < 2; ++nn)                                     \
  _Pragma("unroll") for (int s = 0; s < 2; ++s)                                        \
      acc[(mh)*2 + mm][(nh)*2 + nn] = __builtin_amdgcn_mfma_f32_16x16x32_bf16(         \
          af[(mh)*2 + mm][s], bg[(nh)*2 + nn][s], acc[(mh)*2 + mm][(nh)*2 + nn], 0, 0, 0);

#define PHASE_TAILH(MH, NH)                                      \
  __builtin_amdgcn_s_barrier();                                  \
  asm volatile("s_waitcnt lgkmcnt(0)" ::: "memory");             \
  __builtin_amdgcn_sched_barrier(0);                             \
  __builtin_amdgcn_s_setprio(1);                                 \
  QUADH(MH, NH);                                                 \
  __builtin_amdgcn_s_setprio(0);                                 \
  __builtin_amdgcn_s_barrier();

__device__ __forceinline__ void core8h(const char* Ab, size_t lda2, const char* Bb,
                                       size_t ldb2, int nt, char* sA, char* sB,
                                       f32x4 (&acc)[4][4], int w, int lane) {
  const int wr = w >> 2, wc = w & 3;
  const int fr = lane & 15, foB = (lane >> 4) << 4;
  const int brow = (wc & 1) << 6;
  const char* gB1 = Bb + (size_t)128 * ldb2;
  bf16x8 af[4][2], bg[4][2];

  stage_half(Ab, lda2, 0, sA + 0, w, lane);
  stage_half(Bb, ldb2, 0, sB + 0, w, lane);
  stage_half(gB1, ldb2, 0, sB + 16384, w, lane);
  if (nt > 1) {
    stage_half(Ab, lda2, 128, sA + 16384, w, lane);
    asm volatile("s_waitcnt vmcnt(2)" ::: "memory");
  } else {
    asm volatile("s_waitcnt vmcnt(0)" ::: "memory");
  }
  __builtin_amdgcn_sched_barrier(0);
  __builtin_amdgcn_s_barrier();

  for (int t = 0; t < nt; ++t) {
    const int buf = t & 1;
    const char* cA = sA + buf * 16384;
    const char* cB = sB + buf * 32768 + (wc >> 1) * 16384;
    char* nA = sA + buf * 16384;
    char* nB = sB + (buf ^ 1) * 32768;
    const int kb1 = (t + 1) << 7, kb2 = (t + 2) << 7;
    const bool stB = (t + 1 < nt), stA = (t + 2 < nt);

#pragma unroll
    for (int m = 0; m < 2; ++m)
#pragma unroll
      for (int s = 0; s < 2; ++s)
        af[m][s] = *frag_at(cA, wr * 64 + m * 16 + fr, s * 64 + foB);
#pragma unroll
    for (int n = 0; n < 2; ++n)
#pragma unroll
      for (int s = 0; s < 2; ++s)
        bg[n][s] = *frag_at(cB, brow + n * 16 + fr, s * 64 + foB);
    if (stB) stage_half(Bb, ldb2, kb1, nB + 0, w, lane);
    PHASE_TAILH(0, 0)

#pragma unroll
    for (int m = 2; m < 4; ++m)
#pragma unroll
      for (int s = 0; s < 2; ++s)
        af[m][s] = *frag_at(cA, wr * 64 + m * 16 + fr, s * 64 + foB);
    if (stB) stage_half(gB1, ldb2, kb1, nB + 16384, w, lane);
    PHASE_TAILH(1, 0)

#pragma unroll
    for (int n = 2; n < 4; ++n)
#pragma unroll
      for (int s = 0; s < 2; ++s)
        bg[n][s] = *frag_at(cB, brow + n * 16 + fr, s * 64 + foB);
    if (stA) stage_half(Ab, lda2, kb2, nA, w, lane);
    PHASE_TAILH(0, 1)

    if (t < nt - 1) {
      if (stA) {
        asm volatile("s_waitcnt vmcnt(2)" ::: "memory");
      } else {
        asm volatile("s_waitcnt vmcnt(0)" ::: "memory");
      }
      __builtin_amdgcn_sched_barrier(0);
    }
    PHASE_TAILH(1, 1)
  }
}

// ---- B-only-staging variant: A fixed in LDS (sG, 16 KB per K-tile) ----
__device__ __forceinline__ void core8h_ldsA(const char* sG, const char* Bb, size_t ldb2,
                                            int nt, char* sB, f32x4 (&acc)[4][4],
                                            int w, int lane) {
  const int wr = w >> 2, wc = w & 3;
  const int fr = lane & 15, foB = (lane >> 4) << 4;
  const int brow = (wc & 1) << 6;
  const char* gB1 = Bb + (size_t)128 * ldb2;
  bf16x8 af[4][2], bg[4][2];

  stage_half(Bb, ldb2, 0, sB + 0, w, lane);
  stage_half(gB1, ldb2, 0, sB + 16384, w, lane);
  asm volatile("s_waitcnt vmcnt(0)" ::: "memory");
  __builtin_amdgcn_sched_barrier(0);
  __builtin_amdgcn_s_barrier();

  for (int t = 0; t < nt; ++t) {
    const int buf = t & 1;
    const char* cA = sG + t * 16384;
    const char* cB = sB + buf * 32768 + (wc >> 1) * 16384;
    char* nB = sB + (buf ^ 1) * 32768;
    if (t + 1 < nt) {
      stage_half(Bb, ldb2, (t + 1) << 7, nB + 0, w, lane);
      stage_half(gB1, ldb2, (t + 1) << 7, nB + 16384, w, lane);
    }
#pragma unroll
    for (int m = 0; m < 4; ++m)
#pragma unroll
      for (int s = 0; s < 2; ++s)
        af[m][s] = *frag_at(cA, wr * 64 + m * 16 + fr, s * 64 + foB);
#pragma unroll
    for (int n = 0; n < 4; ++n)
#pragma unroll
      for (int s = 0; s < 2; ++s)
        bg[n][s] = *frag_at(cB, brow + n * 16 + fr, s * 64 + foB);
    __builtin_amdgcn_s_setprio(1);
#pragma unroll
    for (int m = 0; m < 4; ++m)
#pragma unroll
      for (int n = 0; n < 4; ++n)
#pragma unroll
        for (int s = 0; s < 2; ++s)
          acc[m][n] = __builtin_amdgcn_mfma_f32_16x16x32_bf16(af[m][s], bg[n][s],
                                                              acc[m][n], 0, 0, 0);
    __builtin_amdgcn_s_setprio(0);
    if (t + 1 < nt) {
      asm volatile("s_waitcnt vmcnt(0)" ::: "memory");
      __builtin_amdgcn_sched_barrier(0);
      __builtin_amdgcn_s_barrier();
    }
  }
}

#define ACC4_INIT                                    \
  f32x4 acc[4][4];                                   \
  _Pragma("unroll") for (int m_ = 0; m_ < 4; ++m_)   \
  _Pragma("unroll") for (int n_ = 0; n_ < 4; ++n_)   \
      acc[m_][n_] = f32x4{0.f, 0.f, 0.f, 0.f};

#define ACC4_ZERO                                    \
  _Pragma("unroll") for (int m_ = 0; m_ < 4; ++m_)   \
  _Pragma("unroll") for (int n_ = 0; n_ < 4; ++n_)   \
      acc[m_][n_] = f32x4{0.f, 0.f, 0.f, 0.f};

// ---- z-fused qkvt (exact R9) ----
__global__ __launch_bounds__(512, 2) void k8_qkvt(const ushort* __restrict__ xb,
                                                  const ushort* __restrict__ wt,
                                                  ushort* __restrict__ qb,
                                                  ushort* __restrict__ kkb,
                                                  ushort* __restrict__ Kt,
                                                  ushort* __restrict__ Vt,
                                                  float* __restrict__ zsumH) {
  extern __shared__ char smem[];
  const int o = blockIdx.x;
  const int wg = (o & 7) * 64 + (o >> 3);  // bijective: 512 % 8 == 0
  const int mt = wg >> 2, ct = wg & 3;
  const int tid = threadIdx.x, w = tid >> 6, lane = tid & 63;
  const int wr = w >> 2, wc = w & 3;
  const int fr = lane & 15, foB = (lane >> 4) << 4, q4 = (lane >> 4) << 2;
  const char* Ab = (const char*)(xb + (size_t)mt * 128 * 512);
  const char* Bz[3];
  Bz[0] = (const char*)(wt + (size_t)ct * 65536);
  Bz[1] = (const char*)(wt + 262144 + (size_t)ct * 65536);
  Bz[2] = (const char*)(wt + 524288 + (size_t)ct * 65536);
  char* sA = smem;
  char* sB0 = smem + 32768;
  char* sB1 = smem + 65536;
  char* sB2 = smem + 98304;

  f32x4 acc[3][4][2];
#pragma unroll
  for (int z = 0; z < 3; ++z)
#pragma unroll
    for (int m = 0; m < 4; ++m)
#pragma unroll
      for (int n = 0; n < 2; ++n) acc[z][m][n] = f32x4{0.f, 0.f, 0.f, 0.f};

  stage_half(Ab, 1024, 0, sA, w, lane);
  stage_half(Bz[0], 1024, 0, sB0, w, lane);
  stage_half(Bz[1], 1024, 0, sB1, w, lane);
  stage_half(Bz[2], 1024, 0, sB2, w, lane);
  asm volatile("s_waitcnt vmcnt(0)" ::: "memory");
  __builtin_amdgcn_sched_barrier(0);
  __builtin_amdgcn_s_barrier();

  for (int t = 0; t < 8; ++t) {
    const int buf = t & 1;
    const int bo = buf << 14, nbo = (buf ^ 1) << 14;
    if (t + 1 < 8) {
      const int kb = (t + 1) << 7;
      stage_half(Ab, 1024, kb, sA + nbo, w, lane);
      stage_half(Bz[0], 1024, kb, sB0 + nbo, w, lane);
      stage_half(Bz[1], 1024, kb, sB1 + nbo, w, lane);
      stage_half(Bz[2], 1024, kb, sB2 + nbo, w, lane);
    }
    bf16x8 af[4][2], bg[3][2][2];
#pragma unroll
    for (int m = 0; m < 4; ++m)
#pragma unroll
      for (int s = 0; s < 2; ++s)
        af[m][s] = *frag_at(sA + bo, wr * 64 + m * 16 + fr, s * 64 + foB);
#pragma unroll
    for (int z = 0; z < 3; ++z)
#pragma unroll
      for (int n = 0; n < 2; ++n)
#pragma unroll
        for (int s = 0; s < 2; ++s)
          bg[z][n][s] = *frag_at((z == 0 ? sB0 : z == 1 ? sB1 : sB2) + bo,
                                 wc * 32 + n * 16 + fr, s * 64 + foB);
    __builtin_amdgcn_s_setprio(1);
#pragma unroll
    for (int z = 0; z < 3; ++z)
#pragma unroll
      for (int m = 0; m < 4; ++m)
#pragma unroll
        for (int n = 0; n < 2; ++n)
#pragma unroll
          for (int s = 0; s < 2; ++s)
            acc[z][m][n] = __builtin_amdgcn_mfma_f32_16x16x32_bf16(af[m][s], bg[z][n][s],
                                                                   acc[z][m][n], 0, 0, 0);
    __builtin_amdgcn_s_setprio(0);
    if (t + 1 < 8) {
      asm volatile("s_waitcnt vmcnt(0)" ::: "memory");
    }
    __builtin_amdgcn_sched_barrier(0);
    __builtin_amdgcn_s_barrier();
  }

  const size_t row0 = (size_t)mt * 128 + wr * 64;  // t index
  const size_t col0 = (size_t)ct * 128 + wc * 32;  // d index
  // z=0: q = phi(..)
#pragma unroll
  for (int m = 0; m < 4; ++m)
#pragma unroll
    for (int n = 0; n < 2; ++n)
#pragma unroll
      for (int r = 0; r < 4; ++r) {
        float v = acc[0][m][n][r];
        v = v > 0.f ? v + 1.f : __expf(v);
        qb[(row0 + m * 16 + q4 + r) * 512 + col0 + n * 16 + fr] = bfbits(v);
      }
  // z=2: Vt transposed
#pragma unroll
  for (int m = 0; m < 4; ++m)
#pragma unroll
    for (int n = 0; n < 2; ++n) {
      ushort4 ov;
      ov.x = bfbits(acc[2][m][n][0]);
      ov.y = bfbits(acc[2][m][n][1]);
      ov.z = bfbits(acc[2][m][n][2]);
      ov.w = bfbits(acc[2][m][n][3]);
      *(ushort4*)&Vt[(col0 + n * 16 + fr) * 16384 + row0 + m * 16 + q4] = ov;
    }
  // z=1: kk normal + Kt transposed + col sums
  float zs[2] = {0.f, 0.f};
#pragma unroll
  for (int m = 0; m < 4; ++m)
#pragma unroll
    for (int n = 0; n < 2; ++n) {
      float ph[4];
#pragma unroll
      for (int r = 0; r < 4; ++r) {
        float v = acc[1][m][n][r];
        ph[r] = v > 0.f ? v + 1.f : __expf(v);
        kkb[(row0 + m * 16 + q4 + r) * 512 + col0 + n * 16 + fr] = bfbits(ph[r]);
        zs[n] += ph[r];
      }
      ushort4 ov;
      ov.x = bfbits(ph[0]); ov.y = bfbits(ph[1]); ov.z = bfbits(ph[2]); ov.w = bfbits(ph[3]);
      *(ushort4*)&Kt[(col0 + n * 16 + fr) * 16384 + row0 + m * 16 + q4] = ov;
    }
#pragma unroll
  for (int n = 0; n < 2; ++n) {
    zs[n] += __shfl_xor(zs[n], 16, 64);
    zs[n] += __shfl_xor(zs[n], 32, 64);
  }
  float* zbuf = (float*)smem;  // final K-loop barrier protects reuse
  if (lane < 16) {
#pragma unroll
    for (int n = 0; n < 2; ++n) zbuf[wr * 128 + wc * 32 + n * 16 + fr] = zs[n];
  }
  __syncthreads();
  if (tid < 128)
    zsumH[(size_t)mt * 512 + ct * 128 + tid] = zbuf[tid] + zbuf[128 + tid];
}

// ---- St = exclusive chunk prefix of Vt_c Kt_c^T ----
// b = blockIdx.x & 7 pins chunk b to XCD b: working set A 2MB + B 2MB = 4MB L2.
__global__ __launch_bounds__(512, 2) void k8_mtst(const ushort* __restrict__ Kt,
                                                  const ushort* __restrict__ Vt,
                                                  ushort* __restrict__ Mt) {
  __shared__ __align__(16) char smem[49152];  // A 2x16K @0, B 2x8K @32768
  const int o = blockIdx.x;
  const int b = o & 7, r8 = o >> 3;
  const int et = r8 >> 3, dt = r8 & 7;
  const int tid = threadIdx.x, w = tid >> 6, lane = tid & 63;
  const int wr = w >> 2, wc = w & 3, fr = lane & 15;
  const int foB = (lane >> 4) << 4, q4 = (lane >> 4) << 2;
  const char* Ab = (const char*)(Vt + (size_t)et * 128 * 16384 + b * 2048);
  const char* Bb = (const char*)(Kt + (size_t)dt * 64 * 16384 + b * 2048);
  f32x4 acc[4];
#pragma unroll
  for (int m = 0; m < 4; ++m) acc[m] = f32x4{0.f, 0.f, 0.f, 0.f};

  stage_half(Ab, 32768, 0, smem, w, lane);
  stage_q64(Bb, 32768, 0, smem + 32768, tid);
  asm volatile("s_waitcnt vmcnt(0)" ::: "memory");
  __builtin_amdgcn_sched_barrier(0);
  __builtin_amdgcn_s_barrier();

  const int colg = dt * 64 + wc * 16 + fr;
  for (int kk = 0; kk < 32; ++kk) {
    const int c = kk >> 2, buf = kk & 1;
    if ((kk & 3) == 0) {
      ushort* Sc = Mt + (size_t)(b * 8 + c) * 262144 + colg;
#pragma unroll
      for (int m = 0; m < 4; ++m)
#pragma unroll
        for (int r = 0; r < 4; ++r)
          Sc[(size_t)(et * 128 + wr * 64 + m * 16 + q4 + r) * 512] = bfbits(acc[m][r]);
    }
    if (kk + 1 < 32) {
      const int k0b = ((kk + 1) >> 2) * 512 + ((kk + 1) & 3) * 128;
      stage_half(Ab, 32768, k0b, smem + ((buf ^ 1) << 14), w, lane);
      stage_q64(Bb, 32768, k0b, smem + 32768 + ((buf ^ 1) << 13), tid);
    }
    const char* cA = smem + (buf << 14);
    const char* cB = smem + 32768 + (buf << 13);
    bf16x8 af[4][2], bg[2];
#pragma unroll
    for (int s = 0; s < 2; ++s) bg[s] = *frag_at(cB, wc * 16 + fr, s * 64 + foB);
#pragma unroll
    for (int m = 0; m < 4; ++m)
#pragma unroll
      for (int s = 0; s < 2; ++s)
        af[m][s] = *frag_at(cA, wr * 64 + m * 16 + fr, s * 64 + foB);
    __builtin_amdgcn_s_setprio(1);
#pragma unroll
    for (int m = 0; m < 4; ++m)
#pragma unroll
      for (int s = 0; s < 2; ++s)
        acc[m] = __builtin_amdgcn_mfma_f32_16x16x32_bf16(af[m][s], bg[s], acc[m], 0, 0, 0);
    __builtin_amdgcn_s_setprio(0);
    asm volatile("s_waitcnt vmcnt(0)" ::: "memory");
    __builtin_amdgcn_sched_barrier(0);
    __builtin_amdgcn_s_barrier();
  }
}

// ---- y uber-kernel: G(LDS) + den in-block + y = (Q St^T + G Vt^T)/den ----
__global__ __launch_bounds__(512, 2) void k8_y(const ushort* __restrict__ qb,
                                               const ushort* __restrict__ kkb,
                                               const ushort* __restrict__ St,
                                               const ushort* __restrict__ Vt,
                                               const float* __restrict__ zsumH,
                                               ushort* __restrict__ Y) {
  extern __shared__ char smem[];
  const int o = blockIdx.x;
  const int wg = (o & 7) * 32 + (o >> 3);
  const int bc = wg >> 2, rh = (wg >> 1) & 1, ch = wg & 1;
  const int b = bc >> 3, c = bc & 7;
  const int tid = threadIdx.x, w = tid >> 6, lane = tid & 63;
  const int wr = w >> 2, wc = w & 3, fr = lane & 15, q4 = (lane >> 4) << 2;
  char* sA = smem + 65536;
  char* sB = smem + 98304;
  const char* qptr = (const char*)(qb + (size_t)bc * 131072 + (size_t)rh * 65536);

  ACC4_INIT
  core8h(qptr, 1024, (const char*)(kkb + (size_t)bc * 131072), 1024, 8, sA, sB, acc, w, lane);

  float rs[4][4];
#pragma unroll
  for (int m = 0; m < 4; ++m)
#pragma unroll
    for (int r = 0; r < 4; ++r) rs[m][r] = 0.f;
#pragma unroll
  for (int m = 0; m < 4; ++m)
#pragma unroll
    for (int n = 0; n < 4; ++n)
#pragma unroll
      for (int r = 0; r < 4; ++r) {
        int rowL = wr * 64 + m * 16 + q4 + r;
        int col = wc * 64 + n * 16 + fr;
        float v = (col <= rh * 128 + rowL) ? acc[m][n][r] : 0.f;
        rs[m][r] += v;
        int byte = (rowL << 7) + ((col & 63) << 1);
        byte ^= (rowL & 7) << 4;
        *(__bf16*)(smem + (wc << 14) + byte) = (__bf16)v;
      }
#pragma unroll
  for (int m = 0; m < 4; ++m)
#pragma unroll
    for (int r = 0; r < 4; ++r) {
      rs[m][r] += __shfl_xor(rs[m][r], 1, 64);
      rs[m][r] += __shfl_xor(rs[m][r], 2, 64);
      rs[m][r] += __shfl_xor(rs[m][r], 4, 64);
      rs[m][r] += __shfl_xor(rs[m][r], 8, 64);
    }
  float* red = (float*)sA;
  float* zpl = red + 512;
  float* dend = zpl + 512;
  if (fr == 0) {
#pragma unroll
    for (int m = 0; m < 4; ++m)
#pragma unroll
      for (int r = 0; r < 4; ++r) red[wc * 128 + wr * 64 + m * 16 + q4 + r] = rs[m][r];
  }
  {
    float a = 0.f;
    for (int cp = 0; cp < c; ++cp)
      a += zsumH[(size_t)((b * 8 + cp) * 2) * 512 + tid] +
           zsumH[(size_t)((b * 8 + cp) * 2 + 1) * 512 + tid];
    zpl[tid] = a;
  }
  __syncthreads();
  {
    int rl = tid >> 2, quarter = tid & 3;
    int trow = bc * 256 + rh * 128 + rl;
    const ushort* qrow = qb + (size_t)trow * 512 + quarter * 128;
    const float* zq = zpl + quarter * 128;
    float s = 0.f;
    for (int j = 0; j < 128; j += 8) {
      ushort8 qv = *(const ushort8*)&qrow[j];
#pragma unroll
      for (int u = 0; u < 8; ++u) s = fmaf(bff(qv[u]), zq[j + u], s);
    }
    s += __shfl_xor(s, 1, 64);
    s += __shfl_xor(s, 2, 64);
    if (quarter == 0)
      dend[rl] = s + red[rl] + red[128 + rl] + red[256 + rl] + red[384 + rl] + 1e-6f;
  }
  __syncthreads();
  float dinv[4][4];
#pragma unroll
  for (int m = 0; m < 4; ++m)
#pragma unroll
    for (int r = 0; r < 4; ++r) dinv[m][r] = 1.f / dend[wr * 64 + m * 16 + q4 + r];
  __syncthreads();

  ACC4_ZERO
  core8h(qptr, 1024, (const char*)(St + (size_t)bc * 262144 + (size_t)ch * 131072), 1024, 8,
         sA, sB, acc, w, lane);
  core8h_ldsA(smem, (const char*)(Vt + (size_t)ch * 256 * 16384 + (size_t)bc * 256), 32768,
              rh ? 4 : 2, sB, acc, w, lane);

#pragma unroll
  for (int m = 0; m < 4; ++m)
#pragma unroll
    for (int n = 0; n < 4; ++n)
#pragma unroll
      for (int r = 0; r < 4; ++r) {
        size_t row = (size_t)bc * 256 + rh * 128 + wr * 64 + m * 16 + q4 + r;
        size_t col = (size_t)ch * 256 + wc * 64 + n * 16 + fr;
        Y[row * 512 + col] = bfbits(acc[m][n][r] * dinv[m][r]);
      }
}

// ---- out = Y WpT^T (fp32) : 256 blocks, core8h ----
__global__ __launch_bounds__(512, 2) void k8_out(const ushort* __restrict__ Y,
                                                 const ushort* __restrict__ wt,
                                                 float* __restrict__ out) {
  extern __shared__ char smem[];
  const int o = blockIdx.x;
  const int wg = (o & 7) * 32 + (o >> 3);
  const int mt = wg >> 1, ct = wg & 1;
  const int tid = threadIdx.x, w = tid >> 6, lane = tid & 63;
  ACC4_INIT
  core8h((const char*)(Y + (size_t)mt * 65536), 1024,
         (const char*)(wt + 786432 + (size_t)ct * 131072), 1024, 8,
         smem, smem + 32768, acc, w, lane);
  const int wr = w >> 2, wc = w & 3, fr = lane & 15, q4 = (lane >> 4) << 2;
  const size_t row0 = (size_t)mt * 128 + wr * 64;
  const size_t col0 = (size_t)ct * 256 + wc * 64;
#pragma unroll
  for (int m = 0; m < 4; ++m)
#pragma unroll
    for (int n = 0; n < 4; ++n)
#pragma unroll
      for (int r = 0; r < 4; ++r)
        out[(row0 + m * 16 + q4 + r) * 512 + col0 + n * 16 + fr] = acc[m][n][r];
}

// ---- x -> bf16 (4096 blocks) + W -> W^T bf16 (256 blocks) ----
__global__ __launch_bounds__(256) void k_pre(const float* __restrict__ x,
                                             const float* __restrict__ Wq,
                                             const float* __restrict__ Wk,
                                             const float* __restrict__ Wv,
                                             const float* __restrict__ Wp,
                                             ushort* __restrict__ xb,
                                             ushort* __restrict__ wt) {
  __shared__ float tile[64][65];
  if (blockIdx.x < 4096) {
    size_t i = ((size_t)blockIdx.x * 256 + threadIdx.x) * 8;
    float4 f0 = *(const float4*)&x[i], f1 = *(const float4*)&x[i + 4];
    ushort8 ov;
    ov[0] = bfbits(f0.x); ov[1] = bfbits(f0.y); ov[2] = bfbits(f0.z); ov[3] = bfbits(f0.w);
    ov[4] = bfbits(f1.x); ov[5] = bfbits(f1.y); ov[6] = bfbits(f1.z); ov[7] = bfbits(f1.w);
    *(ushort8*)&xb[i] = ov;
  } else {
    const int g = blockIdx.x - 4096;
    const int bz = g >> 6, rem = g & 63, bxw = rem >> 3, byw = rem & 7;
    const float* src = bz == 0 ? Wq : bz == 1 ? Wk : bz == 2 ? Wv : Wp;
    ushort* dst = wt + (size_t)bz * 262144;
    const int d0 = bxw * 64, n0 = byw * 64;
    const int tr = threadIdx.x >> 4, tc = (threadIdx.x & 15) << 2;
#pragma unroll
    for (int it = 0; it < 4; ++it) {
      float4 f = *(const float4*)&src[(size_t)(d0 + it * 16 + tr) * 512 + n0 + tc];
      tile[it * 16 + tr][tc + 0] = f.x;
      tile[it * 16 + tr][tc + 1] = f.y;
      tile[it * 16 + tr][tc + 2] = f.z;
      tile[it * 16 + tr][tc + 3] = f.w;
    }
    __syncthreads();
#pragma unroll
    for (int it = 0; it < 4; ++it) {
      int n = it * 16 + tr;
      ushort4 ov;
      ov.x = bfbits(tile[tc + 0][n]);
      ov.y = bfbits(tile[tc + 1][n]);
      ov.z = bfbits(tile[tc + 2][n]);
      ov.w = bfbits(tile[tc + 3][n]);
      *(ushort4*)&dst[(size_t)(n0 + n) * 512 + d0 + tc] = ov;
    }
  }
}

extern "C" void kernel_launch(void* const* d_in, const int* in_sizes, int n_in,
                              void* d_out, int out_size, void* d_ws, size_t ws_size,
                              hipStream_t stream) {
  const float* x  = (const float*)d_in[0];
  const float* Wq = (const float*)d_in[1];
  const float* Wk = (const float*)d_in[2];
  const float* Wv = (const float*)d_in[3];
  const float* Wp = (const float*)d_in[4];
  float* out = (float*)d_out;
  char* ws8 = (char*)d_ws;
  if (ws_size < WS_NEED) return;

  ushort* xb  = (ushort*)(ws8 + OFF_XB);
  ushort* wt  = (ushort*)(ws8 + OFF_WT);
  ushort* qb  = (ushort*)(ws8 + OFF_Q);
  ushort* kkb = (ushort*)(ws8 + OFF_KK);
  ushort* Kt  = (ushort*)(ws8 + OFF_KT);
  ushort* Vt  = (ushort*)(ws8 + OFF_VT);
  ushort* Mt  = (ushort*)(ws8 + OFF_MT);
  ushort* Y   = (ushort*)(ws8 + OFF_Y);
  float*  zpH = (float*)(ws8 + OFF_ZP);

  constexpr int SMEM_QKVT = 131072, SMEM_H = 98304, SMEM_Y = 163840;
  hipFuncSetAttribute((const void*)k8_qkvt, hipFuncAttributeMaxDynamicSharedMemorySize, SMEM_QKVT);
  hipFuncSetAttribute((const void*)k8_y,    hipFuncAttributeMaxDynamicSharedMemorySize, SMEM_Y);
  hipFuncSetAttribute((const void*)k8_out,  hipFuncAttributeMaxDynamicSharedMemorySize, SMEM_H);

  k_pre<<<4352, 256, 0, stream>>>(x, Wq, Wk, Wv, Wp, xb, wt);
  k8_qkvt<<<512, 512, SMEM_QKVT, stream>>>(xb, wt, qb, kkb, Kt, Vt, zpH);
  k8_mtst<<<256, 512, 0, stream>>>(Kt, Vt, Mt);
  k8_y<<<256, 512, SMEM_Y, stream>>>(qb, kkb, Mt, Vt, zpH, Y);
  k8_out<<<256, 512, SMEM_H, stream>>>(Y, wt, out);
}